// Round 10
// baseline (328.525 us; speedup 1.0000x reference)
//
#include <hip/hip_runtime.h>
#include <math.h>

#define EMBED   2048
#define NEXP    64
#define BATCHN  16384
#define RT      32              // rows per block
#define NT_A    256
#define LCAP    16380           // flag-list capacity (fits in 64KB ws slot)
#define MARGIN_THRESH 4e-4f     // bf16-split logit err ~1e-5 abs; 40x margin

typedef float  f32x4  __attribute__((ext_vector_type(4)));
typedef __bf16 bf16x8 __attribute__((ext_vector_type(8)));

// split fp32 -> bf16 hi + bf16 lo (x ~= hi + lo, residual ~2^-18 |x|)
__device__ __forceinline__ void cvt8(const float4& a, const float4& b,
                                     bf16x8& h, bf16x8& l) {
    float f[8] = {a.x, a.y, a.z, a.w, b.x, b.y, b.z, b.w};
    #pragma unroll
    for (int j = 0; j < 8; ++j) {
        __bf16 hh = (__bf16)f[j];
        h[j] = hh;
        l[j] = (__bf16)(f[j] - (float)hh);   // x - hi exact in fp32
    }
}

__device__ __forceinline__ bf16x8 cfrag(float v) {
    bf16x8 r;
    #pragma unroll
    for (int j = 0; j < 8; ++j) r[j] = (__bf16)v;
    return r;
}

// async 16B global->LDS copy (dest = wave-uniform base + lane*16, src per-lane)
__device__ __forceinline__ void gload_lds16(const float* g, float* lds) {
    __builtin_amdgcn_global_load_lds(
        (const __attribute__((address_space(1))) unsigned int*)g,
        (__attribute__((address_space(3))) unsigned int*)lds,
        16, 0, 0);
}

// ---------------- Kernel 0: pack W -> hi/lo B-fragment layout, zero flag count ----
__global__ __launch_bounds__(256)
void pack_w_kernel(const float* __restrict__ W, __bf16* __restrict__ Wh,
                   __bf16* __restrict__ Wl, int* __restrict__ flagcnt)
{
    const int g = blockIdx.x * 256 + threadIdx.x;    // 16384 = 4 tiles * 64 kcg * 64 lanes
    if (g == 0) *flagcnt = 0;
    const int tile = g >> 12, rem = g & 4095;
    const int kc = rem >> 6, ln = rem & 63;
    const int e = tile * 16 + (ln & 15);
    const int k = kc * 32 + (ln >> 4) * 8;
    const float* wp = W + (size_t)e * EMBED + k;
    float4 a = *(const float4*)wp, b = *(const float4*)(wp + 4);
    bf16x8 h, l;
    cvt8(a, b, h, l);
    *(bf16x8*)(Wh + (size_t)g * 8) = h;              // coalesced 16B stores
    *(bf16x8*)(Wl + (size_t)g * 8) = l;
}

// ---------------- Kernel A (templated ablation, NO scratch memory) ----------------
// MODE 0: full (R8-identical, real output). MODE 1: NO_W (W frags constant;
// x stage/read/cvt path intact). MODE 2: NO_X (x path removed; W loads + MFMA
// + barrier rhythm intact). MODE!=0 skips the epilogue entirely and keeps acc
// live via asm (no out/flag writes, no extra workspace). REP=2 on probes so a
// dominant phase exceeds the ~78us fill dispatches -> visible in top-5.
template<int MODE, int REP>
__global__ __launch_bounds__(NT_A, 2)
void gemm_topk_kernel(const float* __restrict__ x, const __bf16* __restrict__ Wh,
                      const __bf16* __restrict__ Wl, const float* __restrict__ bias,
                      float* __restrict__ out, int* __restrict__ flagcnt,
                      int* __restrict__ flaglist)
{
    __shared__ __align__(16) float Xs[2][RT * 128];  // raw fp32 stage, 2 x 16 KB
    __shared__ float lg[RT][64];                     // 8 KB

    const int tid  = threadIdx.x;
    const int lane = tid & 63;
    const int w    = tid >> 6;                     // wave = expert tile
    const int row0 = blockIdx.x * RT;

    // staging: wave w fills 16B-units [w*256,(w+1)*256); dest linear, source
    // carries the inverse XOR swizzle (involution) => conflict-free ds_read.
    const float* gsrc[4];
    #pragma unroll
    for (int i = 0; i < 4; ++i) {
        const int d   = (w * 4 + i) * 64 + lane;
        const int row = d >> 5;
        const int cu  = (d & 31) ^ (row & 7);
        gsrc[i] = x + (size_t)(row0 + row) * EMBED + cu * 4;
    }

    const __bf16* whp = Wh + ((size_t)w * 64 * 64 + lane) * 8;   // + kcg*512
    const __bf16* wlp = Wl + ((size_t)w * 64 * 64 + lane) * 8;

    f32x4 acc0 = {0.f, 0.f, 0.f, 0.f};
    f32x4 acc1 = {0.f, 0.f, 0.f, 0.f};

    const int r0i = lane & 15;
    const int r1i = r0i + 16;
    const int sw  = r0i & 7;

    #pragma unroll 1
    for (int rep = 0; rep < REP; ++rep) {
        if (MODE != 2) {   // prologue: stage 0 async
            #pragma unroll
            for (int i = 0; i < 4; ++i)
                gload_lds16(gsrc[i], &Xs[0][(w * 4 + i) * 256]);
        }
        __syncthreads();

        #pragma unroll 1
        for (int s = 0; s < 16; ++s) {
            const int cur = s & 1;
            if (MODE != 2 && s < 15) {
                #pragma unroll
                for (int i = 0; i < 4; ++i)
                    gload_lds16(gsrc[i] + (s + 1) * 128, &Xs[cur ^ 1][(w * 4 + i) * 256]);
            }
            const float* xs = &Xs[cur][0];
            #pragma unroll
            for (int kc = 0; kc < 4; ++kc) {
                bf16x8 ah0, al0, ah1, al1;
                if (MODE != 2) {
                    const int cb = kc * 8 + ((lane >> 4) & 3) * 2;
                    float4 a0 = *(const float4*)&xs[r0i * 128 + ((cb    ) ^ sw) * 4];
                    float4 b0 = *(const float4*)&xs[r0i * 128 + ((cb + 1) ^ sw) * 4];
                    float4 a1 = *(const float4*)&xs[r1i * 128 + ((cb    ) ^ sw) * 4];
                    float4 b1 = *(const float4*)&xs[r1i * 128 + ((cb + 1) ^ sw) * 4];
                    cvt8(a0, b0, ah0, al0);
                    cvt8(a1, b1, ah1, al1);
                } else {
                    ah0 = cfrag(0.25f); al0 = cfrag(0.001f);
                    ah1 = cfrag(0.5f);  al1 = cfrag(0.002f);
                }
                bf16x8 bh, bl;
                if (MODE != 1) {
                    bh = *(const bf16x8*)(whp + (size_t)(s * 4 + kc) * 512);
                    bl = *(const bf16x8*)(wlp + (size_t)(s * 4 + kc) * 512);
                } else {
                    bh = cfrag(0.5f); bl = cfrag(0.03125f);
                }
                acc0 = __builtin_amdgcn_mfma_f32_16x16x32_bf16(ah0, bh, acc0, 0, 0, 0);
                acc0 = __builtin_amdgcn_mfma_f32_16x16x32_bf16(ah0, bl, acc0, 0, 0, 0);
                acc0 = __builtin_amdgcn_mfma_f32_16x16x32_bf16(al0, bh, acc0, 0, 0, 0);
                acc1 = __builtin_amdgcn_mfma_f32_16x16x32_bf16(ah1, bh, acc1, 0, 0, 0);
                acc1 = __builtin_amdgcn_mfma_f32_16x16x32_bf16(ah1, bl, acc1, 0, 0, 0);
                acc1 = __builtin_amdgcn_mfma_f32_16x16x32_bf16(al1, bh, acc1, 0, 0, 0);
            }
            __syncthreads();
        }
    }

    if (MODE != 0) {   // probes: keep results live, write NOTHING
        #pragma unroll
        for (int q = 0; q < 4; ++q) {
            asm volatile("" :: "v"(acc0[q]));
            asm volatile("" :: "v"(acc1[q]));
        }
        return;        // uniform for the whole grid of this instantiation
    }

    // D layout (m89-verified): col = lane&15, row_local = (lane>>4)*4 + reg (+16 rh=1)
    const float bb = bias[w * 16 + (lane & 15)];
    #pragma unroll
    for (int q = 0; q < 4; ++q) {
        lg[(lane >> 4) * 4 + q][w * 16 + (lane & 15)]      = acc0[q] + bb;
        lg[16 + (lane >> 4) * 4 + q][w * 16 + (lane & 15)] = acc1[q] + bb;
    }
    __syncthreads();

    #pragma unroll 1
    for (int r = 0; r < 8; ++r) {
        const int row_l = w * 8 + r;
        float v1 = lg[row_l][lane], v2 = -INFINITY, v3 = -INFINITY;
        int   i1 = lane, i2 = 0;
        #pragma unroll
        for (int m = 1; m <= 32; m <<= 1) {
            const float o1  = __shfl_xor(v1, m, 64);
            const int   oi1 = __shfl_xor(i1, m, 64);
            const float o2  = __shfl_xor(v2, m, 64);
            const int   oi2 = __shfl_xor(i2, m, 64);
            const float o3  = __shfl_xor(v3, m, 64);
            if (o1 > v1) {
                float nv2; int ni2; float nv3;
                if (v1 > o2) { nv2 = v1; ni2 = i1;  nv3 = fmaxf(v2, o2); }
                else         { nv2 = o2; ni2 = oi2; nv3 = fmaxf(v1, o3); }
                v1 = o1; i1 = oi1; v2 = nv2; i2 = ni2; v3 = nv3;
            } else {
                if (o1 > v2) { v3 = fmaxf(v2, o2); v2 = o1; i2 = oi1; }
                else         { v3 = fmaxf(v3, o1); }
            }
        }
        if (lane == 0) {
            const int row = row0 + row_l;
            const float margin = fminf(v1 - v2, v2 - v3);
            if (margin < MARGIN_THRESH) {
                const int idx = atomicAdd(flagcnt, 1);
                if (idx < LCAP) flaglist[idx] = row;
            }
            const float e2  = __expf(v2 - v1);
            const float inv = 1.0f / (1.0f + e2);
            *(float2*)&out[row * 2]              = make_float2(inv, e2 * inv);
            *(float2*)&out[2 * BATCHN + row * 2] = make_float2((float)i1, (float)i2);
        }
    }
}

// ---------------- Kernel B: exact f64 recheck of flagged rows (compacted list) ----
__global__ __launch_bounds__(256, 2)
void recheck_kernel(const float* __restrict__ x, const float* __restrict__ W,
                    const float* __restrict__ bias, float* __restrict__ out,
                    const int* __restrict__ flagcnt, const int* __restrict__ flaglist)
{
    __shared__ double sh[NEXP];
    const int tid = threadIdx.x;
    const int e = tid >> 2, q = tid & 3;
    int cnt = *flagcnt;
    if (cnt > LCAP) cnt = LCAP;

    #pragma unroll 1
    for (int i = blockIdx.x; i < cnt; i += gridDim.x) {
        const int row = flaglist[i];
        const float* xr = x + (size_t)row * EMBED + q * 512;
        const float* wr = W + (size_t)e * EMBED + q * 512;
        double s = 0.0;
        #pragma unroll 4
        for (int k = 0; k < 512; k += 4) {
            const float4 xv = *(const float4*)(xr + k);
            const float4 wv = *(const float4*)(wr + k);
            s += (double)xv.x * (double)wv.x;
            s += (double)xv.y * (double)wv.y;
            s += (double)xv.z * (double)wv.z;
            s += (double)xv.w * (double)wv.w;
        }
        s += __shfl_xor(s, 1, 64);
        s += __shfl_xor(s, 2, 64);
        if (q == 0) sh[e] = s + (double)bias[e];
        __syncthreads();
        if (tid == 0) {
            double v1 = -1e300, v2 = -1e300; int i1 = 0, i2 = 0;
            for (int ee = 0; ee < NEXP; ++ee) {
                const double v = sh[ee];
                if (v > v1)      { v2 = v1; i2 = i1; v1 = v; i1 = ee; }
                else if (v > v2) { v2 = v; i2 = ee; }
            }
            const double ex  = exp(v2 - v1);
            const double inv = 1.0 / (1.0 + ex);
            out[row * 2]                  = (float)inv;
            out[row * 2 + 1]              = (float)(ex * inv);
            out[2 * BATCHN + row * 2]     = (float)i1;
            out[2 * BATCHN + row * 2 + 1] = (float)i2;
        }
        __syncthreads();
    }
}

extern "C" void kernel_launch(void* const* d_in, const int* in_sizes, int n_in,
                              void* d_out, int out_size, void* d_ws, size_t ws_size,
                              hipStream_t stream) {
    const float* x = (const float*)d_in[0];
    const float* W = (const float*)d_in[1];
    const float* b = (const float*)d_in[2];
    float* out = (float*)d_out;
    // ws layout (576KB, proven): [0,4) flagcnt | [16,64K) flaglist
    //                            [64K,320K) Wh | [320K,576K) Wl
    int*    flagcnt  = (int*)d_ws;
    int*    flaglist = flagcnt + 4;
    __bf16* Wh = (__bf16*)((char*)d_ws + 65536);
    __bf16* Wl = (__bf16*)((char*)d_ws + 65536 + 262144);

    pack_w_kernel<<<dim3(64), dim3(256), 0, stream>>>(W, Wh, Wl, flagcnt);
    // ablation probes: no memory writes at all (epilogue skipped, acc kept via asm)
    gemm_topk_kernel<1, 2><<<dim3(BATCHN / RT), dim3(NT_A), 0, stream>>>(x, Wh, Wl, b, out, flagcnt, flaglist);
    gemm_topk_kernel<2, 2><<<dim3(BATCHN / RT), dim3(NT_A), 0, stream>>>(x, Wh, Wl, b, out, flagcnt, flaglist);
    // real kernel (R8-identical path)
    gemm_topk_kernel<0, 1><<<dim3(BATCHN / RT), dim3(NT_A), 0, stream>>>(x, Wh, Wl, b, out, flagcnt, flaglist);
    recheck_kernel<<<dim3(128), dim3(256), 0, stream>>>(x, W, b, out, flagcnt, flaglist);
}